// Round 1
// baseline (2280.417 us; speedup 1.0000x reference)
//
#include <hip/hip_runtime.h>
#include <hip/hip_bf16.h>
#include <math.h>

// Problem dims (fixed)
constexpr int B = 64, S = 512, H = 1024, NC = 20, NN = 15, NCN = 35, OPN = 5;
constexpr float NEG = -1e12f;

// ---------------- workspace layout (float offsets) ----------------
constexpr size_t F_LC   = 0;                          // [B][2H] lc = [left_childs | cur_emb]
constexpr size_t F_TL   = F_LC   + (size_t)B*2*H;     // [B][H] cur@Wl^T + bl
constexpr size_t F_TLG  = F_TL   + (size_t)B*H;
constexpr size_t F_TR   = F_TLG  + (size_t)B*H;
constexpr size_t F_TRG  = F_TR   + (size_t)B*H;
constexpr size_t F_NODE = F_TRG  + (size_t)B*H;
constexpr size_t F_U    = F_NODE + (size_t)B*H;       // node@Wa1^T + ba
constexpr size_t F_V    = F_U    + (size_t)B*H;       // [4096][H] chunk of enc@Wa2^T
constexpr size_t F_E    = F_V    + (size_t)4096*H;    // energies [B][S]
constexpr size_t F_AT   = F_E    + (size_t)B*S;       // attn [B][S]
constexpr size_t F_CP   = F_AT   + (size_t)B*S;       // ctx partials [B][4][H]
constexpr size_t F_NC   = F_CP   + (size_t)B*4*H;     // [B][2H] [node|ctx]
constexpr size_t F_LEAF = F_NC   + (size_t)B*2*H;     // [B][H]
constexpr size_t F_EN   = F_LEAF + (size_t)B*H;       // [2240][3H]
constexpr size_t F_HN   = F_EN   + (size_t)B*NCN*3*H; // [2240][H]
constexpr size_t F_EO   = F_HN   + (size_t)B*NCN*H;   // [320][3H]
constexpr size_t F_HO   = F_EO   + (size_t)B*OPN*3*H; // [320][H]
constexpr size_t F_MASK = F_HO   + (size_t)B*OPN*H;   // int[B]

// ---------------- left_mask decode (bool-vs-int32 layout detector) ----------------
__global__ void k_decode_mask(const unsigned char* __restrict__ lm, int* __restrict__ out)
{
    int t = threadIdx.x; // 64 threads
    __shared__ int isByteLayout;
    if (t == 0) {
        // int32 little-endian 0/1 data has all bytes at (i&3)!=0 equal to zero.
        int nz = 0;
        for (int i = 1; i < 64; ++i)
            if ((i & 3) != 0 && lm[i]) nz++;
        isByteLayout = nz;
    }
    __syncthreads();
    out[t] = isByteLayout ? (int)lm[t] : ((const int*)lm)[t];
}

// ---------------- small elementwise kernels ----------------
__global__ __launch_bounds__(256) void k_build_lc(const float* __restrict__ lch,
                                                  const float* __restrict__ cur,
                                                  float* __restrict__ lc)
{
    int idx = blockIdx.x * 256 + threadIdx.x;  // over B*H
    int b = idx >> 10, h = idx & 1023;
    lc[(size_t)b * 2 * H + h]     = lch[idx];
    lc[(size_t)b * 2 * H + H + h] = cur[idx];
}

__device__ __forceinline__ float sigmoidf(float x) { return 1.f / (1.f + expf(-x)); }

__global__ __launch_bounds__(256) void k_node(const float* __restrict__ tl, const float* __restrict__ tlg,
                                              const float* __restrict__ tr, const float* __restrict__ trg,
                                              const int* __restrict__ mask,
                                              float* __restrict__ node_ws, float* __restrict__ out_node)
{
    int idx = blockIdx.x * 256 + threadIdx.x;  // over B*H
    int b = idx >> 10;
    float v;
    if (mask[b]) v = tanhf(tr[idx]) * sigmoidf(trg[idx]);
    else         v = tanhf(tl[idx]) * sigmoidf(tlg[idx]);
    node_ws[idx] = v;
    out_node[idx] = v;
}

// ---------------- generic fp32 GEMM: C = act(A @ W^T + bias) ----------------
// A [M,K] row-major (lda), W [N,K] row-major (ldw). 64x64 tile, 256 threads, K%32==0.
template<int ACT>
__global__ __launch_bounds__(256) void gemm_at(const float* __restrict__ A, int lda,
                                               const float* __restrict__ W, int ldw,
                                               const float* __restrict__ bias,
                                               float* __restrict__ C, int ldc, int K)
{
    __shared__ float As[32][68];
    __shared__ float Bs[32][68];
    const int tid = threadIdx.x;
    const int n0 = blockIdx.x * 64;
    const int m0 = blockIdx.y * 64;
    const int tx = tid & 15, ty = tid >> 4;
    const int lr = tid >> 2;           // 0..63 row to load
    const int lk = (tid & 3) * 8;      // k offset 0,8,16,24
    float acc[4][4] = {};
    const float* ap = A + (size_t)(m0 + lr) * lda + lk;
    const float* wp = W + (size_t)(n0 + lr) * ldw + lk;
    for (int k0 = 0; k0 < K; k0 += 32) {
        float4 a0 = *(const float4*)(ap + k0);
        float4 a1 = *(const float4*)(ap + k0 + 4);
        float4 b0 = *(const float4*)(wp + k0);
        float4 b1 = *(const float4*)(wp + k0 + 4);
        __syncthreads();
        As[lk+0][lr]=a0.x; As[lk+1][lr]=a0.y; As[lk+2][lr]=a0.z; As[lk+3][lr]=a0.w;
        As[lk+4][lr]=a1.x; As[lk+5][lr]=a1.y; As[lk+6][lr]=a1.z; As[lk+7][lr]=a1.w;
        Bs[lk+0][lr]=b0.x; Bs[lk+1][lr]=b0.y; Bs[lk+2][lr]=b0.z; Bs[lk+3][lr]=b0.w;
        Bs[lk+4][lr]=b1.x; Bs[lk+5][lr]=b1.y; Bs[lk+6][lr]=b1.z; Bs[lk+7][lr]=b1.w;
        __syncthreads();
        #pragma unroll
        for (int kk = 0; kk < 32; ++kk) {
            const float4 av = *(const float4*)&As[kk][tx * 4];
            const float4 bv = *(const float4*)&Bs[kk][ty * 4];
            acc[0][0] = fmaf(av.x, bv.x, acc[0][0]);
            acc[0][1] = fmaf(av.x, bv.y, acc[0][1]);
            acc[0][2] = fmaf(av.x, bv.z, acc[0][2]);
            acc[0][3] = fmaf(av.x, bv.w, acc[0][3]);
            acc[1][0] = fmaf(av.y, bv.x, acc[1][0]);
            acc[1][1] = fmaf(av.y, bv.y, acc[1][1]);
            acc[1][2] = fmaf(av.y, bv.z, acc[1][2]);
            acc[1][3] = fmaf(av.y, bv.w, acc[1][3]);
            acc[2][0] = fmaf(av.z, bv.x, acc[2][0]);
            acc[2][1] = fmaf(av.z, bv.y, acc[2][1]);
            acc[2][2] = fmaf(av.z, bv.z, acc[2][2]);
            acc[2][3] = fmaf(av.z, bv.w, acc[2][3]);
            acc[3][0] = fmaf(av.w, bv.x, acc[3][0]);
            acc[3][1] = fmaf(av.w, bv.y, acc[3][1]);
            acc[3][2] = fmaf(av.w, bv.z, acc[3][2]);
            acc[3][3] = fmaf(av.w, bv.w, acc[3][3]);
        }
    }
    #pragma unroll
    for (int i = 0; i < 4; ++i) {
        int row = m0 + tx * 4 + i;
        #pragma unroll
        for (int j = 0; j < 4; ++j) {
            int col = n0 + ty * 4 + j;
            float v = acc[i][j];
            if (bias) v += bias[col];
            if (ACT == 1) v = tanhf(v);
            C[(size_t)row * ldc + col] = v;
        }
    }
}

// ---------------- attention energy: energies[b,s] = bs + sum_h Ws[h]*tanh(u[b,h]+v[m,h]) ----------------
__global__ __launch_bounds__(256) void k_energy(const float* __restrict__ v, const float* __restrict__ u,
                                                const float* __restrict__ Wsv, const float* __restrict__ bsv,
                                                const int* __restrict__ seqm,
                                                float* __restrict__ energ, int m0)
{
    int lane = threadIdx.x & 63;
    int row = m0 + blockIdx.x * 4 + (threadIdx.x >> 6);  // global (b*S+s)
    int b = row >> 9;
    const float* vp = v + (size_t)(row - m0) * H;
    const float* up = u + (size_t)b * H;
    float p = 0.f;
    for (int h = lane; h < H; h += 64)
        p += Wsv[h] * tanhf(up[h] + vp[h]);
    #pragma unroll
    for (int off = 32; off; off >>= 1) p += __shfl_down(p, off, 64);
    if (lane == 0)
        energ[row] = (seqm[row] == 0) ? NEG : (p + bsv[0]);
}

__global__ __launch_bounds__(256) void k_softmax(const float* __restrict__ e, float* __restrict__ attn)
{
    int b = blockIdx.x, tid = threadIdx.x;
    __shared__ float red[256];
    float m = -INFINITY;
    for (int s = tid; s < S; s += 256) m = fmaxf(m, e[b * S + s]);
    red[tid] = m; __syncthreads();
    for (int w = 128; w; w >>= 1) { if (tid < w) red[tid] = fmaxf(red[tid], red[tid + w]); __syncthreads(); }
    m = red[0];
    __syncthreads();
    float sum = 0.f;
    for (int s = tid; s < S; s += 256) { float x = expf(e[b * S + s] - m); attn[b * S + s] = x; sum += x; }
    red[tid] = sum; __syncthreads();
    for (int w = 128; w; w >>= 1) { if (tid < w) red[tid] += red[tid + w]; __syncthreads(); }
    float inv = 1.f / red[0];
    for (int s = tid; s < S; s += 256) attn[b * S + s] *= inv;
}

__global__ __launch_bounds__(256) void k_ctx_part(const float* __restrict__ attn, const float* __restrict__ enc,
                                                  float* __restrict__ part)
{
    int b = blockIdx.x, sc = blockIdx.y, tid = threadIdx.x;
    __shared__ float a[128];
    if (tid < 128) a[tid] = attn[b * S + sc * 128 + tid];
    __syncthreads();
    float acc0 = 0, acc1 = 0, acc2 = 0, acc3 = 0;
    const float* ep = enc + ((size_t)b * S + sc * 128) * H + tid;
    for (int s = 0; s < 128; ++s) {
        float w = a[s];
        acc0 = fmaf(w, ep[(size_t)s * H +   0], acc0);
        acc1 = fmaf(w, ep[(size_t)s * H + 256], acc1);
        acc2 = fmaf(w, ep[(size_t)s * H + 512], acc2);
        acc3 = fmaf(w, ep[(size_t)s * H + 768], acc3);
    }
    float* pp = part + ((size_t)b * 4 + sc) * H + tid;
    pp[0] = acc0; pp[256] = acc1; pp[512] = acc2; pp[768] = acc3;
}

__global__ __launch_bounds__(256) void k_ctx_reduce(const float* __restrict__ part, const float* __restrict__ node_ws,
                                                    float* __restrict__ out_ctx, float* __restrict__ nc)
{
    int b = blockIdx.x, tid = threadIdx.x;
    #pragma unroll
    for (int q = 0; q < 4; ++q) {
        int h = tid + q * 256;
        float v = part[((size_t)b * 4 + 0) * H + h] + part[((size_t)b * 4 + 1) * H + h]
                + part[((size_t)b * 4 + 2) * H + h] + part[((size_t)b * 4 + 3) * H + h];
        out_ctx[(size_t)b * H + h] = v;
        nc[(size_t)b * 2 * H + H + h] = v;
        nc[(size_t)b * 2 * H + h] = node_ws[(size_t)b * H + h];
    }
}

// ---------------- score-head input builders ----------------
__global__ __launch_bounds__(256) void k_build_En(const float* __restrict__ leaf, const float* __restrict__ cemb,
                                                  const float* __restrict__ pades,
                                                  float* __restrict__ En, float* __restrict__ out_cn)
{
    int row = blockIdx.x;          // 0..2239
    int b = row / NCN, i = row - b * NCN;
    int tid = threadIdx.x;
    #pragma unroll
    for (int q = 0; q < 4; ++q) {
        int h = tid + q * 256;
        float lf = leaf[(size_t)b * H + h];
        float cn = (i < NC) ? cemb[(size_t)i * H + h]
                            : pades[((size_t)b * NN + (i - NC)) * H + h];
        out_cn[(size_t)row * H + h] = cn;
        En[(size_t)row * 3 * H + h]         = lf;
        En[(size_t)row * 3 * H + H + h]     = cn;
        En[(size_t)row * 3 * H + 2 * H + h] = lf * cn;
    }
}

__global__ __launch_bounds__(256) void k_build_Eo(const float* __restrict__ leaf, const float* __restrict__ oemb,
                                                  float* __restrict__ Eo)
{
    int row = blockIdx.x;          // 0..319
    int b = row / OPN, i = row - b * OPN;
    int tid = threadIdx.x;
    #pragma unroll
    for (int q = 0; q < 4; ++q) {
        int h = tid + q * 256;
        float lf = leaf[(size_t)b * H + h];
        float cn = oemb[(size_t)i * H + h];
        Eo[(size_t)row * 3 * H + h]         = lf;
        Eo[(size_t)row * 3 * H + H + h]     = cn;
        Eo[(size_t)row * 3 * H + 2 * H + h] = lf * cn;
    }
}

__global__ __launch_bounds__(256) void k_copy_op(const float* __restrict__ oemb, float* __restrict__ out)
{
    int idx = blockIdx.x * 256 + threadIdx.x;  // 5120
    out[idx] = oemb[idx];
}

// ---------------- final score dot: out[row] = mask? dot(h[row], Wsc) : NEG ----------------
__global__ __launch_bounds__(256) void k_score(const float* __restrict__ hsrc, const float* __restrict__ Wsc,
                                               const int* __restrict__ mask, float* __restrict__ out)
{
    int lane = threadIdx.x & 63;
    int row = blockIdx.x * 4 + (threadIdx.x >> 6);
    const float* hp = hsrc + (size_t)row * H;
    float p = 0.f;
    for (int h = lane; h < H; h += 64) p += Wsc[h] * hp[h];
    #pragma unroll
    for (int off = 32; off; off >>= 1) p += __shfl_down(p, off, 64);
    if (lane == 0)
        out[row] = (mask && mask[row] == 0) ? NEG : p;
}

// ---------------- launch ----------------
extern "C" void kernel_launch(void* const* d_in, const int* in_sizes, int n_in,
                              void* d_out, int out_size, void* d_ws, size_t ws_size,
                              hipStream_t stream)
{
    const float* cur   = (const float*)d_in[0];
    const float* lch   = (const float*)d_in[1];
    const unsigned char* lmask = (const unsigned char*)d_in[2];
    const float* enc   = (const float*)d_in[3];
    const float* pades = (const float*)d_in[4];
    const int*   seqm  = (const int*)d_in[5];
    const int*   masknums = (const int*)d_in[6];
    const float* cemb  = (const float*)d_in[7];
    const float* oemb  = (const float*)d_in[8];
    const float* Wl  = (const float*)d_in[9];   const float* bl   = (const float*)d_in[10];
    const float* Wlg = (const float*)d_in[11];  const float* blg  = (const float*)d_in[12];
    const float* Wr  = (const float*)d_in[13];  const float* br   = (const float*)d_in[14];
    const float* Wrg = (const float*)d_in[15];  const float* brg  = (const float*)d_in[16];
    const float* Wleaf = (const float*)d_in[17];const float* bleaf= (const float*)d_in[18];
    const float* Wa  = (const float*)d_in[19];  const float* ba   = (const float*)d_in[20];
    const float* Wsv = (const float*)d_in[21];  const float* bsv  = (const float*)d_in[22];
    const float* Wna = (const float*)d_in[23];  const float* bna  = (const float*)d_in[24];
    const float* Wns = (const float*)d_in[25];
    const float* Woa = (const float*)d_in[26];  const float* boa  = (const float*)d_in[27];
    const float* Wos = (const float*)d_in[28];

    float* out = (float*)d_out;
    float* o_num  = out;               // [64,35]
    float* o_op   = out + 2240;        // [64,5]
    float* o_node = out + 2560;        // [64,1,1024]
    float* o_ctx  = out + 68096;       // [64,1,1024]
    float* o_cn   = out + 133632;      // [64,35,1024]
    float* o_oe   = out + 2427392;     // [5,1024]

    float* ws = (float*)d_ws;
    int* maskws = (int*)(ws + F_MASK);

    k_decode_mask<<<1, 64, 0, stream>>>(lmask, maskws);
    k_build_lc<<<256, 256, 0, stream>>>(lch, cur, ws + F_LC);

    // node gating GEMMs (store pre-activations)
    gemm_at<0><<<dim3(16, 1), 256, 0, stream>>>(cur, H,        Wl,  H,     bl,  ws + F_TL,  H, H);
    gemm_at<0><<<dim3(16, 1), 256, 0, stream>>>(cur, H,        Wlg, H,     blg, ws + F_TLG, H, H);
    gemm_at<0><<<dim3(16, 1), 256, 0, stream>>>(ws + F_LC, 2*H, Wr,  2*H,  br,  ws + F_TR,  H, 2*H);
    gemm_at<0><<<dim3(16, 1), 256, 0, stream>>>(ws + F_LC, 2*H, Wrg, 2*H,  brg, ws + F_TRG, H, 2*H);
    k_node<<<256, 256, 0, stream>>>(ws + F_TL, ws + F_TLG, ws + F_TR, ws + F_TRG, maskws,
                                    ws + F_NODE, o_node);

    // u = node @ Wa1^T + ba
    gemm_at<0><<<dim3(16, 1), 256, 0, stream>>>(ws + F_NODE, H, Wa, 2*H, ba, ws + F_U, H, H);

    // v = enc @ Wa2^T (chunked over batch), fused into energies
    for (int c = 0; c < 8; ++c) {
        const float* ac = enc + (size_t)c * 4096 * H;
        gemm_at<0><<<dim3(16, 64), 256, 0, stream>>>(ac, H, Wa + H, 2*H, nullptr, ws + F_V, H, H);
        k_energy<<<1024, 256, 0, stream>>>(ws + F_V, ws + F_U, Wsv, bsv, seqm, ws + F_E, c * 4096);
    }

    k_softmax<<<B, 256, 0, stream>>>(ws + F_E, ws + F_AT);
    k_ctx_part<<<dim3(B, 4), 256, 0, stream>>>(ws + F_AT, enc, ws + F_CP);
    k_ctx_reduce<<<B, 256, 0, stream>>>(ws + F_CP, ws + F_NODE, o_ctx, ws + F_NC);

    // leaf = tanh([node|ctx] @ Wleaf^T + bleaf)
    gemm_at<1><<<dim3(16, 1), 256, 0, stream>>>(ws + F_NC, 2*H, Wleaf, 2*H, bleaf, ws + F_LEAF, H, 2*H);

    // score-head inputs + passthrough outputs
    k_build_En<<<B * NCN, 256, 0, stream>>>(ws + F_LEAF, cemb, pades, ws + F_EN, o_cn);
    k_build_Eo<<<B * OPN, 256, 0, stream>>>(ws + F_LEAF, oemb, ws + F_EO);
    k_copy_op<<<20, 256, 0, stream>>>(oemb, o_oe);

    // hidden = tanh(E @ W^T + b)
    gemm_at<1><<<dim3(16, 35), 256, 0, stream>>>(ws + F_EN, 3*H, Wna, 3*H, bna, ws + F_HN, H, 3*H);
    gemm_at<1><<<dim3(16, 5),  256, 0, stream>>>(ws + F_EO, 3*H, Woa, 3*H, boa, ws + F_HO, H, 3*H);

    // final dots (+ num mask)
    k_score<<<560, 256, 0, stream>>>(ws + F_HN, Wns, masknums, o_num);
    k_score<<<80, 256, 0, stream>>>(ws + F_HO, Wos, nullptr, o_op);
}

// Round 2
// 1135.094 us; speedup vs baseline: 2.0090x; 2.0090x over previous
//
#include <hip/hip_runtime.h>
#include <hip/hip_bf16.h>
#include <math.h>

// Problem dims (fixed)
constexpr int B = 64, S = 512, H = 1024, NC = 20, NN = 15, NCN = 35, OPN = 5;
constexpr float NEG = -1e12f;

typedef __attribute__((ext_vector_type(8))) short bf16x8;
typedef __attribute__((ext_vector_type(4))) float f32x4;
typedef __attribute__((ext_vector_type(4))) unsigned short us4;

// ---------------- workspace layout (float offsets) ----------------
constexpr size_t F_E    = 0;                           // [32768] energies (atomic)
constexpr size_t F_NSC  = F_E    + 32768;              // [2304] num scores (atomic)
constexpr size_t F_OSC  = F_NSC  + 2304;               // [384]  op scores (atomic)
constexpr size_t F_CURP = F_OSC  + 384;                // [128][1024] cur padded
constexpr size_t F_LC   = F_CURP + 131072;             // [128][2048] [left|cur] padded
constexpr size_t F_TL   = F_LC   + 262144;             // [128][1024] each
constexpr size_t F_TLG  = F_TL   + 131072;
constexpr size_t F_TR   = F_TLG  + 131072;
constexpr size_t F_TRG  = F_TR   + 131072;
constexpr size_t F_NODE = F_TRG  + 131072;             // [128][1024] node padded
constexpr size_t F_U    = F_NODE + 131072;             // [128][1024] node@Wa1^T+ba
constexpr size_t F_AT   = F_U    + 131072;             // [64][512] attn
constexpr size_t F_CP   = F_AT   + 32768;              // [64][4][1024] ctx partials
constexpr size_t F_NC   = F_CP   + 262144;             // [128][2048] [node|ctx] padded
constexpr size_t F_LEAF = F_NC   + 262144;             // [128][1024]
constexpr size_t F_EN   = F_LEAF + 131072;             // [2304][3072]
constexpr size_t F_EO   = F_EN   + 2304ull*3072;       // [384][3072]
constexpr size_t F_MASK = F_EO   + 384ull*3072;        // int[64]
// total ~10.2M floats = 40.6 MB

__device__ __forceinline__ float sigmoidf(float x) { return 1.f / (1.f + expf(-x)); }

__device__ __forceinline__ unsigned short f2bf(float f) {
    __hip_bfloat16 h = __float2bfloat16(f);
    return *reinterpret_cast<unsigned short*>(&h);
}

__device__ __forceinline__ us4 cvt4(float4 v) {
    us4 r;
    r.x = f2bf(v.x); r.y = f2bf(v.y); r.z = f2bf(v.z); r.w = f2bf(v.w);
    return r;
}

// ---------------- left_mask decode (bool-vs-int32 layout detector) ----------------
__global__ void k_decode_mask(const unsigned char* __restrict__ lm, int* __restrict__ out)
{
    int t = threadIdx.x; // 64 threads
    __shared__ int isByteLayout;
    if (t == 0) {
        int nz = 0;
        for (int i = 1; i < 64; ++i)
            if ((i & 3) != 0 && lm[i]) nz++;
        isByteLayout = nz;
    }
    __syncthreads();
    out[t] = isByteLayout ? (int)lm[t] : ((const int*)lm)[t];
}

// ================= MFMA GEMM: acc = A(f32,[M,K]) @ W(f32,[N,K])^T, bf16 inputs =================
// MODE 0: C = acc + bias            (f32 store)
// MODE 1: C = tanh(acc + bias)      (f32 store)
// MODE 2: red[row] += sum_col Wred[col] * tanh( U[(row>>ushift)<<10 | col] + acc )   (atomic)
// Tile 128x128, BK=32, 256 threads = 4 waves (2x2 of 64x64), swizzled LDS, M%128==0, N%128==0, K%32==0.
template<int MODE>
__global__ __launch_bounds__(256) void mfma_gemm(
    const float* __restrict__ A, int lda,
    const float* __restrict__ Wt, int ldw, int K,
    const float* __restrict__ bias,
    float* __restrict__ C, int ldc,
    const float* __restrict__ U, int ushift,
    const float* __restrict__ Wred,
    float* __restrict__ red)
{
    __shared__ unsigned short As[4096];   // [128][32] bf16, rows 64B, XOR-swizzled
    __shared__ unsigned short Bs[4096];
    const int tid = threadIdx.x;
    const int m0 = blockIdx.y << 7, n0 = blockIdx.x << 7;
    const int l  = tid & 63, wid = tid >> 6;
    const int wm = wid >> 1, wn = wid & 1;
    const int lr = l & 15, lk = l >> 4;

    f32x4 acc[4][4] = {};

    // fragment LDS byte offsets (swizzle: chunk16 ^= row&3)
    int aoff[4], boff[4];
    #pragma unroll
    for (int i = 0; i < 4; ++i) {
        int ra = (wm << 6) + (i << 4) + lr;
        aoff[i] = (ra << 6) | ((lk << 4) ^ ((ra & 3) << 4));
        int rb = (wn << 6) + (i << 4) + lr;
        boff[i] = (rb << 6) | ((lk << 4) ^ ((rb & 3) << 4));
    }

    // staging: pass p -> row = p*32 + tid>>3, j = tid&7 (8B bf16 chunks, src 16B f32)
    const int srow = tid >> 3, sj = tid & 7;
    const float* Ab = A  + (size_t)(m0 + srow) * lda + (sj << 2);
    const float* Wb = Wt + (size_t)(n0 + srow) * ldw + (sj << 2);

    for (int k0 = 0; k0 < K; k0 += 32) {
        #pragma unroll
        for (int p = 0; p < 4; ++p) {
            int row = (p << 5) + srow;
            int dst = (row << 6) | ((sj << 3) ^ ((row & 3) << 4));
            float4 va = *(const float4*)(Ab + (size_t)(p << 5) * lda + k0);
            float4 vb = *(const float4*)(Wb + (size_t)(p << 5) * ldw + k0);
            *(us4*)((char*)As + dst) = cvt4(va);
            *(us4*)((char*)Bs + dst) = cvt4(vb);
        }
        __syncthreads();
        bf16x8 af[4], bfr[4];
        #pragma unroll
        for (int i = 0; i < 4; ++i) {
            af[i]  = *(const bf16x8*)((const char*)As + aoff[i]);
            bfr[i] = *(const bf16x8*)((const char*)Bs + boff[i]);
        }
        #pragma unroll
        for (int mi = 0; mi < 4; ++mi)
            #pragma unroll
            for (int ni = 0; ni < 4; ++ni)
                acc[mi][ni] = __builtin_amdgcn_mfma_f32_16x16x32_bf16(af[mi], bfr[ni], acc[mi][ni], 0, 0, 0);
        __syncthreads();
    }

    if (MODE <= 1) {
        #pragma unroll
        for (int mi = 0; mi < 4; ++mi) {
            const int gmb = m0 + (wm << 6) + (mi << 4) + (lk << 2);
            #pragma unroll
            for (int ni = 0; ni < 4; ++ni) {
                const int gn = n0 + (wn << 6) + (ni << 4) + lr;
                const float bv = bias ? bias[gn] : 0.f;
                #pragma unroll
                for (int i = 0; i < 4; ++i) {
                    float v = acc[mi][ni][i] + bv;
                    if (MODE == 1) v = tanhf(v);
                    C[(size_t)(gmb + i) * ldc + gn] = v;
                }
            }
        }
    } else {
        #pragma unroll
        for (int mi = 0; mi < 4; ++mi) {
            float p0 = 0.f, p1 = 0.f, p2 = 0.f, p3 = 0.f;
            const int gmb = m0 + (wm << 6) + (mi << 4) + (lk << 2);
            #pragma unroll
            for (int ni = 0; ni < 4; ++ni) {
                const int gn = n0 + (wn << 6) + (ni << 4) + lr;
                const float wv = Wred[gn];
                p0 += wv * tanhf(U[(size_t)(((gmb + 0) >> ushift) << 10) + gn] + acc[mi][ni][0]);
                p1 += wv * tanhf(U[(size_t)(((gmb + 1) >> ushift) << 10) + gn] + acc[mi][ni][1]);
                p2 += wv * tanhf(U[(size_t)(((gmb + 2) >> ushift) << 10) + gn] + acc[mi][ni][2]);
                p3 += wv * tanhf(U[(size_t)(((gmb + 3) >> ushift) << 10) + gn] + acc[mi][ni][3]);
            }
            #pragma unroll
            for (int msk = 1; msk < 16; msk <<= 1) {
                p0 += __shfl_xor(p0, msk, 64);
                p1 += __shfl_xor(p1, msk, 64);
                p2 += __shfl_xor(p2, msk, 64);
                p3 += __shfl_xor(p3, msk, 64);
            }
            if (lr == 0) {
                atomicAdd(&red[gmb + 0], p0);
                atomicAdd(&red[gmb + 1], p1);
                atomicAdd(&red[gmb + 2], p2);
                atomicAdd(&red[gmb + 3], p3);
            }
        }
    }
}

// ---------------- small kernels ----------------
__global__ __launch_bounds__(256) void k_prep(const float* __restrict__ lch, const float* __restrict__ cur,
                                              float* __restrict__ curp, float* __restrict__ lc)
{
    int idx = blockIdx.x * 256 + threadIdx.x;   // 262144 over [128][2048]
    int b = idx >> 11, c = idx & 2047;
    float v = 0.f;
    if (b < 64) v = (c < 1024) ? lch[(b << 10) + c] : cur[(b << 10) + c - 1024];
    lc[idx] = v;
    if (idx < 131072) {
        int b2 = idx >> 10;
        curp[idx] = (b2 < 64) ? cur[idx] : 0.f;
    }
}

__global__ __launch_bounds__(256) void k_node(const float* __restrict__ tl, const float* __restrict__ tlg,
                                              const float* __restrict__ tr, const float* __restrict__ trg,
                                              const int* __restrict__ mask,
                                              float* __restrict__ node_ws, float* __restrict__ out_node)
{
    int idx = blockIdx.x * 256 + threadIdx.x;   // 131072 over [128][1024]
    int b = idx >> 10;
    float v = 0.f;
    if (b < 64) {
        if (mask[b]) v = tanhf(tr[idx]) * sigmoidf(trg[idx]);
        else         v = tanhf(tl[idx]) * sigmoidf(tlg[idx]);
        out_node[idx] = v;
    }
    node_ws[idx] = v;
}

__global__ __launch_bounds__(256) void k_softmax(const float* __restrict__ e, const int* __restrict__ seqm,
                                                 float* __restrict__ attn)
{
    int b = blockIdx.x, tid = threadIdx.x;
    __shared__ float red[256];
    int i0 = b * S;
    float x0 = seqm[i0 + tid]       ? e[i0 + tid]       : NEG;
    float x1 = seqm[i0 + tid + 256] ? e[i0 + tid + 256] : NEG;
    float m = fmaxf(x0, x1);
    red[tid] = m; __syncthreads();
    for (int w = 128; w; w >>= 1) { if (tid < w) red[tid] = fmaxf(red[tid], red[tid + w]); __syncthreads(); }
    m = red[0]; __syncthreads();
    float e0 = expf(x0 - m), e1 = expf(x1 - m);
    red[tid] = e0 + e1; __syncthreads();
    for (int w = 128; w; w >>= 1) { if (tid < w) red[tid] += red[tid + w]; __syncthreads(); }
    float inv = 1.f / red[0];
    attn[i0 + tid] = e0 * inv;
    attn[i0 + tid + 256] = e1 * inv;
}

__global__ __launch_bounds__(256) void k_ctx_part(const float* __restrict__ attn, const float* __restrict__ enc,
                                                  float* __restrict__ part)
{
    int b = blockIdx.x, sc = blockIdx.y, tid = threadIdx.x;
    __shared__ float a[128];
    if (tid < 128) a[tid] = attn[b * S + sc * 128 + tid];
    __syncthreads();
    float acc0 = 0, acc1 = 0, acc2 = 0, acc3 = 0;
    const float* ep = enc + ((size_t)b * S + sc * 128) * H + tid;
    for (int s = 0; s < 128; ++s) {
        float w = a[s];
        acc0 = fmaf(w, ep[(size_t)s * H +   0], acc0);
        acc1 = fmaf(w, ep[(size_t)s * H + 256], acc1);
        acc2 = fmaf(w, ep[(size_t)s * H + 512], acc2);
        acc3 = fmaf(w, ep[(size_t)s * H + 768], acc3);
    }
    float* pp = part + ((size_t)b * 4 + sc) * H + tid;
    pp[0] = acc0; pp[256] = acc1; pp[512] = acc2; pp[768] = acc3;
}

__global__ __launch_bounds__(256) void k_ctx_reduce(const float* __restrict__ part, const float* __restrict__ node_ws,
                                                    float* __restrict__ out_ctx, float* __restrict__ nc)
{
    int b = blockIdx.x, tid = threadIdx.x;   // grid 128
    #pragma unroll
    for (int q = 0; q < 4; ++q) {
        int h = tid + (q << 8);
        if (b < 64) {
            float v = part[((size_t)b * 4 + 0) * H + h] + part[((size_t)b * 4 + 1) * H + h]
                    + part[((size_t)b * 4 + 2) * H + h] + part[((size_t)b * 4 + 3) * H + h];
            out_ctx[((size_t)b << 10) + h] = v;
            nc[((size_t)b << 11) + 1024 + h] = v;
            nc[((size_t)b << 11) + h] = node_ws[((size_t)b << 10) + h];
        } else {
            nc[((size_t)b << 11) + 1024 + h] = 0.f;
            nc[((size_t)b << 11) + h] = 0.f;
        }
    }
}

__global__ __launch_bounds__(256) void k_build_En(const float* __restrict__ leaf, const float* __restrict__ cemb,
                                                  const float* __restrict__ pades,
                                                  float* __restrict__ En, float* __restrict__ o_cn)
{
    int row = blockIdx.x;          // 0..2303
    int b = row / NCN, i = row - b * NCN;
    int tid = threadIdx.x;
    size_t e0 = (size_t)row * 3072;
    #pragma unroll
    for (int q = 0; q < 4; ++q) {
        int h = tid + (q << 8);
        if (row < B * NCN) {
            float lf = leaf[((size_t)b << 10) + h];
            float cn = (i < NC) ? cemb[((size_t)i << 10) + h]
                                : pades[((size_t)(b * NN + (i - NC)) << 10) + h];
            o_cn[((size_t)row << 10) + h] = cn;
            En[e0 + h] = lf; En[e0 + 1024 + h] = cn; En[e0 + 2048 + h] = lf * cn;
        } else {
            En[e0 + h] = 0.f; En[e0 + 1024 + h] = 0.f; En[e0 + 2048 + h] = 0.f;
        }
    }
}

__global__ __launch_bounds__(256) void k_build_Eo(const float* __restrict__ leaf, const float* __restrict__ oemb,
                                                  float* __restrict__ Eo)
{
    int row = blockIdx.x;          // 0..383
    int b = row / OPN, i = row - b * OPN;
    int tid = threadIdx.x;
    size_t e0 = (size_t)row * 3072;
    #pragma unroll
    for (int q = 0; q < 4; ++q) {
        int h = tid + (q << 8);
        if (row < B * OPN) {
            float lf = leaf[((size_t)b << 10) + h];
            float cn = oemb[((size_t)i << 10) + h];
            Eo[e0 + h] = lf; Eo[e0 + 1024 + h] = cn; Eo[e0 + 2048 + h] = lf * cn;
        } else {
            Eo[e0 + h] = 0.f; Eo[e0 + 1024 + h] = 0.f; Eo[e0 + 2048 + h] = 0.f;
        }
    }
}

__global__ __launch_bounds__(256) void k_copy_op(const float* __restrict__ oemb, float* __restrict__ out)
{
    int idx = blockIdx.x * 256 + threadIdx.x;  // 5120
    out[idx] = oemb[idx];
}

__global__ __launch_bounds__(256) void k_finalize(const float* __restrict__ nsc, const float* __restrict__ osc,
                                                  const int* __restrict__ masknums, float* __restrict__ out)
{
    int idx = blockIdx.x * 256 + threadIdx.x;  // 2560
    if (idx < 2240) out[idx] = masknums[idx] ? nsc[idx] : NEG;
    else            out[idx] = osc[idx - 2240];
}

// ---------------- launch ----------------
extern "C" void kernel_launch(void* const* d_in, const int* in_sizes, int n_in,
                              void* d_out, int out_size, void* d_ws, size_t ws_size,
                              hipStream_t stream)
{
    const float* cur   = (const float*)d_in[0];
    const float* lch   = (const float*)d_in[1];
    const unsigned char* lmask = (const unsigned char*)d_in[2];
    const float* enc   = (const float*)d_in[3];
    const float* pades = (const float*)d_in[4];
    const int*   seqm  = (const int*)d_in[5];
    const int*   masknums = (const int*)d_in[6];
    const float* cemb  = (const float*)d_in[7];
    const float* oemb  = (const float*)d_in[8];
    const float* Wl  = (const float*)d_in[9];   const float* bl   = (const float*)d_in[10];
    const float* Wlg = (const float*)d_in[11];  const float* blg  = (const float*)d_in[12];
    const float* Wr  = (const float*)d_in[13];  const float* br   = (const float*)d_in[14];
    const float* Wrg = (const float*)d_in[15];  const float* brg  = (const float*)d_in[16];
    const float* Wleaf = (const float*)d_in[17];const float* bleaf= (const float*)d_in[18];
    const float* Wa  = (const float*)d_in[19];  const float* ba   = (const float*)d_in[20];
    const float* Wsv = (const float*)d_in[21];  /* bsv cancels in softmax */
    const float* Wna = (const float*)d_in[23];  const float* bna  = (const float*)d_in[24];
    const float* Wns = (const float*)d_in[25];
    const float* Woa = (const float*)d_in[26];  const float* boa  = (const float*)d_in[27];
    const float* Wos = (const float*)d_in[28];

    float* out = (float*)d_out;
    float* o_num  = out;               // [64,35] (+[64,5] op contiguous after)
    float* o_node = out + 2560;        // [64,1,1024]
    float* o_ctx  = out + 68096;       // [64,1,1024]
    float* o_cn   = out + 133632;      // [64,35,1024]
    float* o_oe   = out + 2427392;     // [5,1024]

    float* ws = (float*)d_ws;
    int* maskws = (int*)(ws + F_MASK);

    // zero atomic accumulators (E, NSC, OSC contiguous)
    hipMemsetAsync(ws + F_E, 0, (32768 + 2304 + 384) * sizeof(float), stream);

    k_decode_mask<<<1, 64, 0, stream>>>(lmask, maskws);
    k_prep<<<1024, 256, 0, stream>>>(lch, cur, ws + F_CURP, ws + F_LC);

    // node gating (pre-activations), M padded to 128
    mfma_gemm<0><<<dim3(8, 1), 256, 0, stream>>>(ws + F_CURP, H,  Wl,  H,   H,   bl,  ws + F_TL,  H, nullptr, 0, nullptr, nullptr);
    mfma_gemm<0><<<dim3(8, 1), 256, 0, stream>>>(ws + F_CURP, H,  Wlg, H,   H,   blg, ws + F_TLG, H, nullptr, 0, nullptr, nullptr);
    mfma_gemm<0><<<dim3(8, 1), 256, 0, stream>>>(ws + F_LC, 2*H,  Wr,  2*H, 2*H, br,  ws + F_TR,  H, nullptr, 0, nullptr, nullptr);
    mfma_gemm<0><<<dim3(8, 1), 256, 0, stream>>>(ws + F_LC, 2*H,  Wrg, 2*H, 2*H, brg, ws + F_TRG, H, nullptr, 0, nullptr, nullptr);
    k_node<<<512, 256, 0, stream>>>(ws + F_TL, ws + F_TLG, ws + F_TR, ws + F_TRG, maskws,
                                    ws + F_NODE, o_node);

    // u = node @ Wa1^T + ba
    mfma_gemm<0><<<dim3(8, 1), 256, 0, stream>>>(ws + F_NODE, H, Wa, 2*H, H, ba, ws + F_U, H, nullptr, 0, nullptr, nullptr);

    // energies[b*S+s] = sum_h Ws[h]*tanh(u[b,h] + (enc@Wa2^T)[bs,h])   (fused epilogue, atomic)
    mfma_gemm<2><<<dim3(8, 256), 256, 0, stream>>>(enc, H, Wa + H, 2*H, H, nullptr, nullptr, 0,
                                                   ws + F_U, 9, Wsv, ws + F_E);

    k_softmax<<<B, 256, 0, stream>>>(ws + F_E, seqm, ws + F_AT);
    k_ctx_part<<<dim3(B, 4), 256, 0, stream>>>(ws + F_AT, enc, ws + F_CP);
    k_ctx_reduce<<<128, 256, 0, stream>>>(ws + F_CP, ws + F_NODE, o_ctx, ws + F_NC);

    // leaf = tanh([node|ctx] @ Wleaf^T + bleaf)
    mfma_gemm<1><<<dim3(8, 1), 256, 0, stream>>>(ws + F_NC, 2*H, Wleaf, 2*H, 2*H, bleaf, ws + F_LEAF, H, nullptr, 0, nullptr, nullptr);

    // score-head inputs + passthrough outputs
    k_build_En<<<2304, 256, 0, stream>>>(ws + F_LEAF, cemb, pades, ws + F_EN, o_cn);
    k_build_Eo<<<384, 256, 0, stream>>>(ws + F_LEAF, oemb, ws + F_EO);
    k_copy_op<<<20, 256, 0, stream>>>(oemb, o_oe);

    // head scores: red[row] += sum Wns[col]*tanh(bna[col] + En@Wna^T)
    mfma_gemm<2><<<dim3(8, 18), 256, 0, stream>>>(ws + F_EN, 3*H, Wna, 3*H, 3*H, nullptr, nullptr, 0,
                                                  bna, 30, Wns, ws + F_NSC);
    mfma_gemm<2><<<dim3(8, 3), 256, 0, stream>>>(ws + F_EO, 3*H, Woa, 3*H, 3*H, nullptr, nullptr, 0,
                                                 boa, 30, Wos, ws + F_OSC);

    k_finalize<<<10, 256, 0, stream>>>(ws + F_NSC, ws + F_OSC, masknums, out);
}

// Round 4
// 780.790 us; speedup vs baseline: 2.9207x; 1.4538x over previous
//
#include <hip/hip_runtime.h>
#include <hip/hip_bf16.h>
#include <math.h>

// Problem dims (fixed)
constexpr int B = 64, S = 512, H = 1024, NC = 20, NN = 15, NCN = 35, OPN = 5;
constexpr float NEG = -1e12f;

typedef __attribute__((ext_vector_type(8))) short bf16x8;
typedef __attribute__((ext_vector_type(4))) float f32x4;
typedef __attribute__((ext_vector_type(4))) unsigned short us4;
typedef unsigned short ushort_t;

// ---------------- f32 workspace layout (float offsets) ----------------
constexpr size_t F_E    = 0;                    // [32768] energies (atomic)
constexpr size_t F_NSC  = 32768;                // [2304]
constexpr size_t F_OSC  = 35072;                // [384]
constexpr size_t F_U    = 35456;                // [128][1024]
constexpr size_t F_T4   = 166528;               // [4][128][1024] gating pre-acts
constexpr size_t F_LEAF = 690816;               // [128][1024]
constexpr size_t F_AT   = 821888;               // [64][512]
constexpr size_t F_CP   = 854656;               // [64][4][1024]
constexpr size_t F_MASK = 1116800;              // int[64]
constexpr size_t F32_END = 1116864;

// ---------------- bf16 workspace layout (ushort offsets, base = ws + F32_END) ----
constexpr size_t U_CURP = 0;                    // [128][1024]
constexpr size_t U_LC   = 131072;               // [128][2048]
constexpr size_t U_NODE = 393216;               // [128][1024]
constexpr size_t U_NC   = 524288;               // [128][2048]
// 8 weights contiguous (matches k_cvt_w write order): Wa,Wna,Woa,Wl,Wlg,Wr,Wrg,Wleaf
constexpr size_t U_W8   = 786432;
constexpr size_t W_WA    = 0;                   // [1024][2048]
constexpr size_t W_WNA   = 2097152;             // [1024][3072]
constexpr size_t W_WOA   = 5242880;             // [1024][3072]
constexpr size_t W_WL    = 8388608;             // [1024][1024]
constexpr size_t W_WLG   = 9437184;
constexpr size_t W_WR    = 10485760;            // [1024][2048]
constexpr size_t W_WRG   = 12582912;
constexpr size_t W_WLEAF = 14680064;            // [1024][2048]
constexpr size_t U_W8_END = U_W8 + 16777216;    // 17563648
// fallback: EN/EO right after WOA (gate weights not converted)
constexpr size_t U_EN_FB = U_W8 + W_WL;         // 9175040  [2304][3072]
constexpr size_t U_EO_FB = U_EN_FB + 7077888;   // 16252928 [384][3072]
// full: EN/EO after all weights, then enc
constexpr size_t U_EN_FULL = U_W8_END;          // 17563648
constexpr size_t U_EO_FULL = U_EN_FULL + 7077888; // 24641536
constexpr size_t U_ENC  = U_EO_FULL + 1179648;  // 25821184 [32768][1024]
constexpr size_t U_END_FULL = U_ENC + 33554432; // 59375616

constexpr size_t NEED_FULL = F32_END * 4 + U_END_FULL * 2;   // ~123.2 MB

__device__ __forceinline__ float sigmoidf(float x) { return 1.f / (1.f + expf(-x)); }

__device__ __forceinline__ ushort_t f2bf(float f) {
    __hip_bfloat16 h = __float2bfloat16(f);
    return *reinterpret_cast<ushort_t*>(&h);
}
__device__ __forceinline__ float bf2f(ushort_t u) {
    return __uint_as_float(((unsigned)u) << 16);
}
__device__ __forceinline__ us4 cvt4(float4 v) {
    us4 r; r.x = f2bf(v.x); r.y = f2bf(v.y); r.z = f2bf(v.z); r.w = f2bf(v.w);
    return r;
}

__device__ __forceinline__ void gload16(const void* g, void* l) {
    __builtin_amdgcn_global_load_lds(
        (const __attribute__((address_space(1))) unsigned int*)g,
        (__attribute__((address_space(3))) unsigned int*)l, 16, 0, 0);
}

// ---------------- left_mask decode (bool-vs-int32 layout detector) ----------------
__global__ void k_decode_mask(const unsigned char* __restrict__ lm, int* __restrict__ out)
{
    int t = threadIdx.x;
    __shared__ int isByteLayout;
    if (t == 0) {
        int nz = 0;
        for (int i = 1; i < 64; ++i)
            if ((i & 3) != 0 && lm[i]) nz++;
        isByteLayout = nz;
    }
    __syncthreads();
    out[t] = isByteLayout ? (int)lm[t] : ((const int*)lm)[t];
}

// ================= MFMA tile body =================
// A[M,K] @ W[N,K]^T, 128x128 tile, BK=32, 4 waves (2x2 of 64x64), 16x16x32 bf16 MFMA.
// AF/BF: 0 = bf16 source via global_load_lds (linear LDS), 1 = f32 source reg-staged cvt (XOR-swizzled LDS).
// MODE 0: C = acc+bias; MODE 1: C = tanh(acc+bias);
// MODE 2: red[row] += sum_col Wred[col]*tanh(U[(row>>ushift)<<10|col] + acc)  (atomic)
template<int MODE, int AF, int BF>
__device__ __forceinline__ void tile_body(
    const void* __restrict__ Av, int lda,
    const void* __restrict__ Wv, int ldw, int K,
    const float* __restrict__ bias,
    float* __restrict__ C, int ldc,
    const float* __restrict__ U, int ushift,
    const float* __restrict__ Wred, float* __restrict__ red,
    int m0, int n0, ushort_t* As, ushort_t* Bs)
{
    const int tid = threadIdx.x;
    const int l = tid & 63, wid = tid >> 6;
    const int wm = wid >> 1, wn = wid & 1;
    const int lr = l & 15, lk = l >> 4;

    f32x4 acc[4][4] = {};

    // fragment byte offsets in LDS
    int aoff[4], boff[4];
    #pragma unroll
    for (int i = 0; i < 4; ++i) {
        int ra = (wm << 6) + (i << 4) + lr;
        aoff[i] = AF ? ((ra << 6) | ((lk << 4) ^ ((ra & 3) << 4)))
                     : ((ra << 6) | (lk << 4));
        int rb = (wn << 6) + (i << 4) + lr;
        boff[i] = BF ? ((rb << 6) | ((lk << 4) ^ ((rb & 3) << 4)))
                     : ((rb << 6) | (lk << 4));
    }

    // bf16 gload staging geometry: wave stages LDS rows [wid*32, wid*32+32), 2 issues x 16 rows
    const int gr = (wid << 5) + (l >> 2);
    const int gc = (l & 3) << 3;
    // f32 reg-staging geometry (round-2 verified)
    const int srow = tid >> 3, sj = tid & 7;

    const ushort_t* A16 = (const ushort_t*)Av;
    const float*    A32 = (const float*)Av;
    const ushort_t* W16 = (const ushort_t*)Wv;
    const float*    W32 = (const float*)Wv;

    const ushort_t* ag0 = nullptr; const ushort_t* ag1 = nullptr;
    const float* af32 = nullptr;
    ushort_t* asb0 = As + (wid << 10); ushort_t* asb1 = asb0 + 512;
    if (AF == 0) {
        ag0 = A16 + (size_t)(m0 + gr) * lda + gc;
        ag1 = ag0 + (size_t)16 * lda;
    } else {
        af32 = A32 + (size_t)(m0 + srow) * lda + (sj << 2);
    }
    const ushort_t* wg0 = nullptr; const ushort_t* wg1 = nullptr;
    const float* wf32 = nullptr;
    ushort_t* bsb0 = Bs + (wid << 10); ushort_t* bsb1 = bsb0 + 512;
    if (BF == 0) {
        wg0 = W16 + (size_t)(n0 + gr) * ldw + gc;
        wg1 = wg0 + (size_t)16 * ldw;
    } else {
        wf32 = W32 + (size_t)(n0 + srow) * ldw + (sj << 2);
    }

    for (int k0 = 0; k0 < K; k0 += 32) {
        float4 va[4], vb[4];
        if (AF == 1) {
            #pragma unroll
            for (int p = 0; p < 4; ++p)
                va[p] = *(const float4*)(af32 + (size_t)(p << 5) * lda + k0);
        }
        if (BF == 1) {
            #pragma unroll
            for (int p = 0; p < 4; ++p)
                vb[p] = *(const float4*)(wf32 + (size_t)(p << 5) * ldw + k0);
        }
        __syncthreads();   // all waves done reading previous tile
        if (AF == 0) {
            gload16(ag0 + k0, asb0);
            gload16(ag1 + k0, asb1);
        } else {
            #pragma unroll
            for (int p = 0; p < 4; ++p) {
                int row = (p << 5) + srow;
                int dst = (row << 6) | ((sj << 3) ^ ((row & 3) << 4));
                *(us4*)((char*)As + dst) = cvt4(va[p]);
            }
        }
        if (BF == 0) {
            gload16(wg0 + k0, bsb0);
            gload16(wg1 + k0, bsb1);
        } else {
            #pragma unroll
            for (int p = 0; p < 4; ++p) {
                int row = (p << 5) + srow;
                int dst = (row << 6) | ((sj << 3) ^ ((row & 3) << 4));
                *(us4*)((char*)Bs + dst) = cvt4(vb[p]);
            }
        }
        __syncthreads();   // staged tile visible (vmcnt/lgkmcnt drained by barrier)
        bf16x8 af[4], bfv[4];
        #pragma unroll
        for (int i = 0; i < 4; ++i) {
            af[i]  = *(const bf16x8*)((const char*)As + aoff[i]);
            bfv[i] = *(const bf16x8*)((const char*)Bs + boff[i]);
        }
        #pragma unroll
        for (int mi = 0; mi < 4; ++mi)
            #pragma unroll
            for (int ni = 0; ni < 4; ++ni)
                acc[mi][ni] = __builtin_amdgcn_mfma_f32_16x16x32_bf16(af[mi], bfv[ni], acc[mi][ni], 0, 0, 0);
    }

    if (MODE <= 1) {
        #pragma unroll
        for (int mi = 0; mi < 4; ++mi) {
            const int gmb = m0 + (wm << 6) + (mi << 4) + (lk << 2);
            #pragma unroll
            for (int ni = 0; ni < 4; ++ni) {
                const int gn = n0 + (wn << 6) + (ni << 4) + lr;
                const float bv = bias ? bias[gn] : 0.f;
                #pragma unroll
                for (int i = 0; i < 4; ++i) {
                    float v = acc[mi][ni][i] + bv;
                    if (MODE == 1) v = tanhf(v);
                    C[(size_t)(gmb + i) * ldc + gn] = v;
                }
            }
        }
    } else {
        #pragma unroll
        for (int mi = 0; mi < 4; ++mi) {
            float p0 = 0.f, p1 = 0.f, p2 = 0.f, p3 = 0.f;
            const int gmb = m0 + (wm << 6) + (mi << 4) + (lk << 2);
            #pragma unroll
            for (int ni = 0; ni < 4; ++ni) {
                const int gn = n0 + (wn << 6) + (ni << 4) + lr;
                const float wv = Wred[gn];
                p0 += wv * tanhf(U[(size_t)(((gmb + 0) >> ushift) << 10) + gn] + acc[mi][ni][0]);
                p1 += wv * tanhf(U[(size_t)(((gmb + 1) >> ushift) << 10) + gn] + acc[mi][ni][1]);
                p2 += wv * tanhf(U[(size_t)(((gmb + 2) >> ushift) << 10) + gn] + acc[mi][ni][2]);
                p3 += wv * tanhf(U[(size_t)(((gmb + 3) >> ushift) << 10) + gn] + acc[mi][ni][3]);
            }
            #pragma unroll
            for (int msk = 1; msk < 16; msk <<= 1) {
                p0 += __shfl_xor(p0, msk, 64);
                p1 += __shfl_xor(p1, msk, 64);
                p2 += __shfl_xor(p2, msk, 64);
                p3 += __shfl_xor(p3, msk, 64);
            }
            if (lr == 0) {
                atomicAdd(&red[gmb + 0], p0);
                atomicAdd(&red[gmb + 1], p1);
                atomicAdd(&red[gmb + 2], p2);
                atomicAdd(&red[gmb + 3], p3);
            }
        }
    }
}

// 1-D grid with XCD-chunked swizzle (m204 bijective; nwg % 8 == 0, N = 8 tiles per slab)
template<int MODE, int AF, int BF>
__global__ __launch_bounds__(256) void mfma_gemm(
    const void* __restrict__ Av, int lda,
    const void* __restrict__ Wv, int ldw, int K,
    const float* __restrict__ bias,
    float* __restrict__ C, int ldc,
    const float* __restrict__ U, int ushift,
    const float* __restrict__ Wred, float* __restrict__ red)
{
    __shared__ ushort_t As[4096];
    __shared__ ushort_t Bs[4096];
    const int q = gridDim.x >> 3;
    const int wg = (blockIdx.x & 7) * q + (blockIdx.x >> 3);
    const int m0 = (wg >> 3) << 7, n0 = (wg & 7) << 7;
    tile_body<MODE, AF, BF>(Av, lda, Wv, ldw, K, bias, C, ldc, U, ushift, Wred, red,
                            m0, n0, As, Bs);
}

// fused gating: 4 GEMMs (Wl,Wlg,Wr,Wrg) in one dispatch, grid = 32 blocks
template<int BF>
__global__ __launch_bounds__(256) void gemm_gate4(
    const ushort_t* __restrict__ curp, const ushort_t* __restrict__ lc,
    const void* __restrict__ Wl_, const void* __restrict__ Wlg_,
    const void* __restrict__ Wr_, const void* __restrict__ Wrg_,
    const float* __restrict__ bl_, const float* __restrict__ blg_,
    const float* __restrict__ br_, const float* __restrict__ brg_,
    float* __restrict__ T4)
{
    __shared__ ushort_t As[4096];
    __shared__ ushort_t Bs[4096];
    const int sel = blockIdx.x >> 3;
    const int n0 = (blockIdx.x & 7) << 7;
    const ushort_t* A = (sel < 2) ? curp : lc;
    const int K = (sel < 2) ? 1024 : 2048;
    const void* W = (sel == 0) ? Wl_ : (sel == 1) ? Wlg_ : (sel == 2) ? Wr_ : Wrg_;
    const float* bias = (sel == 0) ? bl_ : (sel == 1) ? blg_ : (sel == 2) ? br_ : brg_;
    float* C = T4 + (size_t)sel * 131072;
    tile_body<0, 0, BF>(A, K, W, K, K, bias, C, 1024, nullptr, 0, nullptr, nullptr,
                        0, n0, As, Bs);
}

// ---------------- conversion kernels ----------------
__global__ __launch_bounds__(256) void k_cvt_w(
    const float* __restrict__ wa, const float* __restrict__ wna, const float* __restrict__ woa,
    const float* __restrict__ wl, const float* __restrict__ wlg, const float* __restrict__ wr,
    const float* __restrict__ wrg, const float* __restrict__ wleaf,
    ushort_t* __restrict__ dst)
{
    const int cum[9] = {0, 2097152, 5242880, 8388608, 9437184, 10485760, 12582912, 14680064, 16777216};
    const float* srcs[8] = {wa, wna, woa, wl, wlg, wr, wrg, wleaf};
    int i4 = (blockIdx.x * 256 + threadIdx.x) << 2;
    int s = 0;
    #pragma unroll
    for (int k = 1; k < 8; ++k) if (i4 >= cum[k]) s = k;
    float4 v = *(const float4*)(srcs[s] + (i4 - cum[s]));
    *(us4*)(dst + i4) = cvt4(v);
}

__global__ __launch_bounds__(256) void k_cvt_enc(const float* __restrict__ enc, ushort_t* __restrict__ dst)
{
    size_t i8 = (size_t)(blockIdx.x * 256 + threadIdx.x) << 3;
    float4 v0 = *(const float4*)(enc + i8);
    float4 v1 = *(const float4*)(enc + i8 + 4);
    *(us4*)(dst + i8) = cvt4(v0);
    *(us4*)(dst + i8 + 4) = cvt4(v1);
}

// ---------------- small kernels ----------------
__global__ __launch_bounds__(256) void k_prep(const float* __restrict__ lch, const float* __restrict__ cur,
                                              ushort_t* __restrict__ curp, ushort_t* __restrict__ lc)
{
    int t = blockIdx.x * 256 + threadIdx.x;   // 0..98303
    if (t < 65536) {
        int i = t << 2; int b = i >> 11, c = i & 2047;
        us4 v = {0, 0, 0, 0};
        if (b < 64) {
            const float* s = (c < 1024) ? lch + (b << 10) + c : cur + (b << 10) + c - 1024;
            v = cvt4(*(const float4*)s);
        }
        *(us4*)(lc + i) = v;
    } else {
        int i = (t - 65536) << 2; int b = i >> 10;
        us4 v = {0, 0, 0, 0};
        if (b < 64) v = cvt4(*(const float4*)(cur + i));
        *(us4*)(curp + i) = v;
    }
}

__global__ __launch_bounds__(256) void k_node(const float* __restrict__ T4, const int* __restrict__ mask,
                                              ushort_t* __restrict__ node_bf, float* __restrict__ out_node)
{
    int t = blockIdx.x * 256 + threadIdx.x;   // 32768 threads over [128][1024]/4
    int i = t << 2; int b = i >> 10;
    us4 vb = {0, 0, 0, 0};
    if (b < 64) {
        const float* tl  = T4 + i;
        const float* tlg = T4 + 131072 + i;
        const float* tr  = T4 + 262144 + i;
        const float* trg = T4 + 393216 + i;
        float4 t_, g_;
        if (mask[b]) { t_ = *(const float4*)tr; g_ = *(const float4*)trg; }
        else         { t_ = *(const float4*)tl; g_ = *(const float4*)tlg; }
        float4 v;
        v.x = tanhf(t_.x) * sigmoidf(g_.x);
        v.y = tanhf(t_.y) * sigmoidf(g_.y);
        v.z = tanhf(t_.z) * sigmoidf(g_.z);
        v.w = tanhf(t_.w) * sigmoidf(g_.w);
        *(float4*)(out_node + i) = v;
        vb = cvt4(v);
    }
    *(us4*)(node_bf + i) = vb;
}

__global__ __launch_bounds__(256) void k_softmax(const float* __restrict__ e, const int* __restrict__ seqm,
                                                 float* __restrict__ attn)
{
    int b = blockIdx.x, tid = threadIdx.x;
    __shared__ float red[256];
    int i0 = b * S;
    float x0 = seqm[i0 + tid]       ? e[i0 + tid]       : NEG;
    float x1 = seqm[i0 + tid + 256] ? e[i0 + tid + 256] : NEG;
    float m = fmaxf(x0, x1);
    red[tid] = m; __syncthreads();
    for (int w = 128; w; w >>= 1) { if (tid < w) red[tid] = fmaxf(red[tid], red[tid + w]); __syncthreads(); }
    m = red[0]; __syncthreads();
    float e0 = expf(x0 - m), e1 = expf(x1 - m);
    red[tid] = e0 + e1; __syncthreads();
    for (int w = 128; w; w >>= 1) { if (tid < w) red[tid] += red[tid + w]; __syncthreads(); }
    float inv = 1.f / red[0];
    attn[i0 + tid] = e0 * inv;
    attn[i0 + tid + 256] = e1 * inv;
}

template<int BF16>
__global__ __launch_bounds__(256) void k_ctx_part(const float* __restrict__ attn, const void* __restrict__ enc,
                                                  float* __restrict__ part)
{
    int b = blockIdx.x, sc = blockIdx.y, tid = threadIdx.x;
    __shared__ float a[128];
    if (tid < 128) a[tid] = attn[b * S + sc * 128 + tid];
    __syncthreads();
    int h0 = tid << 2;
    float ax = 0, ay = 0, az = 0, aw = 0;
    if (BF16) {
        const ushort_t* ep = (const ushort_t*)enc + (((size_t)b * S + sc * 128) << 10) + h0;
        for (int s = 0; s < 128; ++s) {
            float w = a[s];
            us4 v = *(const us4*)(ep + ((size_t)s << 10));
            ax = fmaf(w, bf2f(v.x), ax); ay = fmaf(w, bf2f(v.y), ay);
            az = fmaf(w, bf2f(v.z), az); aw = fmaf(w, bf2f(v.w), aw);
        }
    } else {
        const float* ep = (const float*)enc + (((size_t)b * S + sc * 128) << 10) + h0;
        for (int s = 0; s < 128; ++s) {
            float w = a[s];
            float4 v = *(const float4*)(ep + ((size_t)s << 10));
            ax = fmaf(w, v.x, ax); ay = fmaf(w, v.y, ay);
            az = fmaf(w, v.z, az); aw = fmaf(w, v.w, aw);
        }
    }
    float4 r; r.x = ax; r.y = ay; r.z = az; r.w = aw;
    *(float4*)(part + (((size_t)b * 4 + sc) << 10) + h0) = r;
}

__global__ __launch_bounds__(256) void k_ctx_reduce(const float* __restrict__ part, const ushort_t* __restrict__ node_bf,
                                                    float* __restrict__ out_ctx, ushort_t* __restrict__ nc)
{
    int b = blockIdx.x, tid = threadIdx.x;   // grid 128
    int h0 = tid << 2;
    if (b < 64) {
        float4 p0 = *(const float4*)(part + (((size_t)b * 4 + 0) << 10) + h0);
        float4 p1 = *(const float4*)(part + (((size_t)b * 4 + 1) << 10) + h0);
        float4 p2 = *(const float4*)(part + (((size_t)b * 4 + 2) << 10) + h0);
        float4 p3 = *(const float4*)(part + (((size_t)b * 4 + 3) << 10) + h0);
        float4 v;
        v.x = p0.x + p1.x + p2.x + p3.x;
        v.y = p0.y + p1.y + p2.y + p3.y;
        v.z = p0.z + p1.z + p2.z + p3.z;
        v.w = p0.w + p1.w + p2.w + p3.w;
        *(float4*)(out_ctx + ((size_t)b << 10) + h0) = v;
        *(us4*)(nc + ((size_t)b << 11) + 1024 + h0) = cvt4(v);
        *(us4*)(nc + ((size_t)b << 11) + h0) = *(const us4*)(node_bf + ((size_t)b << 10) + h0);
    } else {
        us4 z = {0, 0, 0, 0};
        *(us4*)(nc + ((size_t)b << 11) + 1024 + h0) = z;
        *(us4*)(nc + ((size_t)b << 11) + h0) = z;
    }
}

__global__ __launch_bounds__(256) void k_build_En(const float* __restrict__ leaf, const float* __restrict__ cemb,
                                                  const float* __restrict__ pades,
                                                  ushort_t* __restrict__ En, float* __restrict__ o_cn)
{
    int row = blockIdx.x;          // 0..2303
    int b = row / NCN, i = row - b * NCN;
    int h0 = threadIdx.x << 2;
    size_t e0 = (size_t)row * 3072;
    if (row < B * NCN) {
        float4 lf = *(const float4*)(leaf + ((size_t)b << 10) + h0);
        float4 cn = (i < NC) ? *(const float4*)(cemb + ((size_t)i << 10) + h0)
                             : *(const float4*)(pades + ((size_t)(b * NN + (i - NC)) << 10) + h0);
        *(float4*)(o_cn + ((size_t)row << 10) + h0) = cn;
        float4 pr; pr.x = lf.x * cn.x; pr.y = lf.y * cn.y; pr.z = lf.z * cn.z; pr.w = lf.w * cn.w;
        *(us4*)(En + e0 + h0) = cvt4(lf);
        *(us4*)(En + e0 + 1024 + h0) = cvt4(cn);
        *(us4*)(En + e0 + 2048 + h0) = cvt4(pr);
    } else {
        us4 z = {0, 0, 0, 0};
        *(us4*)(En + e0 + h0) = z;
        *(us4*)(En + e0 + 1024 + h0) = z;
        *(us4*)(En + e0 + 2048 + h0) = z;
    }
}

__global__ __launch_bounds__(256) void k_build_Eo(const float* __restrict__ leaf, const float* __restrict__ oemb,
                                                  ushort_t* __restrict__ Eo)
{
    int row = blockIdx.x;          // 0..383
    int b = row / OPN, i = row - b * OPN;
    int h0 = threadIdx.x << 2;
    size_t e0 = (size_t)row * 3072;
    if (row < B * OPN) {
        float4 lf = *(const float4*)(leaf + ((size_t)b << 10) + h0);
        float4 cn = *(const float4*)(oemb + ((size_t)i << 10) + h0);
        float4 pr; pr.x = lf.x * cn.x; pr.y = lf.y * cn.y; pr.z = lf.z * cn.z; pr.w = lf.w * cn.w;
        *(us4*)(Eo + e0 + h0) = cvt4(lf);
        *(us4*)(Eo + e0 + 1024 + h0) = cvt4(cn);
        *(us4*)(Eo + e0 + 2048 + h0) = cvt4(pr);
    } else {
        us4 z = {0, 0, 0, 0};
        *(us4*)(Eo + e0 + h0) = z;
        *(us4*)(Eo + e0 + 1024 + h0) = z;
        *(us4*)(Eo + e0 + 2048 + h0) = z;
    }
}

__global__ __launch_bounds__(256) void k_copy_op(const float* __restrict__ oemb, float* __restrict__ out)
{
    int idx = blockIdx.x * 256 + threadIdx.x;  // 5120
    out[idx] = oemb[idx];
}

__global__ __launch_bounds__(256) void k_finalize(const float* __restrict__ nsc, const float* __restrict__ osc,
                                                  const int* __restrict__ masknums, float* __restrict__ out)
{
    int idx = blockIdx.x * 256 + threadIdx.x;  // 2560
    if (idx < 2240) out[idx] = masknums[idx] ? nsc[idx] : NEG;
    else            out[idx] = osc[idx - 2240];
}

// ---------------- launch ----------------
extern "C" void kernel_launch(void* const* d_in, const int* in_sizes, int n_in,
                              void* d_out, int out_size, void* d_ws, size_t ws_size,
                              hipStream_t stream)
{
    const float* cur   = (const float*)d_in[0];
    const float* lch   = (const float*)d_in[1];
    const unsigned char* lmask = (const unsigned char*)d_in[2];
    const float* enc   = (const float*)d_in[3];
    const float* pades = (const float*)d_in[4];
    const int*   seqm  = (const int*)d_in[5];
    const int*   masknums = (const int*)d_in[6];
    const float* cemb  = (const float*)d_in[7];
    const float* oemb  = (const float*)d_in[8];
    const float* Wl  = (const float*)d_in[9];   const float* bl   = (const float*)d_in[10];
    const float* Wlg = (const float*)d_in[11];  const float* blg  = (const float*)d_in[12];
    const float* Wr  = (const float*)d_in[13];  const float* br   = (const float*)d_in[14];
    const float* Wrg = (const float*)d_in[15];  const float* brg  = (const float*)d_in[16];
    const float* Wleaf = (const float*)d_in[17];const float* bleaf= (const float*)d_in[18];
    const float* Wa  = (const float*)d_in[19];  const float* ba   = (const float*)d_in[20];
    const float* Wsv = (const float*)d_in[21];  /* bsv cancels in softmax */
    const float* Wna = (const float*)d_in[23];  const float* bna  = (const float*)d_in[24];
    const float* Wns = (const float*)d_in[25];
    const float* Woa = (const float*)d_in[26];  const float* boa  = (const float*)d_in[27];
    const float* Wos = (const float*)d_in[28];

    float* out = (float*)d_out;
    float* o_node = out + 2560;
    float* o_ctx  = out + 68096;
    float* o_cn   = out + 133632;
    float* o_oe   = out + 2427392;

    float* ws = (float*)d_ws;
    ushort_t* wsu = (ushort_t*)(ws + F32_END);
    int* maskws = (int*)(ws + F_MASK);

    const bool full = ws_size >= NEED_FULL;
    const size_t uEN = full ? U_EN_FULL : U_EN_FB;
    const size_t uEO = full ? U_EO_FULL : U_EO_FB;

    hipMemsetAsync(ws + F_E, 0, (32768 + 2304 + 384) * sizeof(float), stream);
    k_decode_mask<<<1, 64, 0, stream>>>(lmask, maskws);

    // weight conversions: always Wa/Wna/Woa (first 8M elems); full adds Wl..Wleaf (next 8M)
    k_cvt_w<<<full ? 16384 : 8192, 256, 0, stream>>>(Wa, Wna, Woa, Wl, Wlg, Wr, Wrg, Wleaf, wsu + U_W8);
    if (full) k_cvt_enc<<<16384, 256, 0, stream>>>(enc, wsu + U_ENC);

    k_prep<<<384, 256, 0, stream>>>(lch, cur, wsu + U_CURP, wsu + U_LC);

    // fused gating GEMMs -> T4 pre-activations
    if (full)
        gemm_gate4<0><<<32, 256, 0, stream>>>(wsu + U_CURP, wsu + U_LC,
            wsu + U_W8 + W_WL, wsu + U_W8 + W_WLG, wsu + U_W8 + W_WR, wsu + U_W8 + W_WRG,
            bl, blg, br, brg, ws + F_T4);
    else
        gemm_gate4<1><<<32, 256, 0, stream>>>(wsu + U_CURP, wsu + U_LC,
            Wl, Wlg, Wr, Wrg, bl, blg, br, brg, ws + F_T4);

    k_node<<<128, 256, 0, stream>>>(ws + F_T4, maskws, wsu + U_NODE, o_node);

    // u = node @ Wa1^T + ba
    mfma_gemm<0, 0, 0><<<8, 256, 0, stream>>>(wsu + U_NODE, 1024, wsu + U_W8 + W_WA, 2048, 1024,
                                              ba, ws + F_U, 1024, nullptr, 0, nullptr, nullptr);

    // energies (fused epilogue, atomic), XCD-swizzled grid
    if (full)
        mfma_gemm<2, 0, 0><<<2048, 256, 0, stream>>>(wsu + U_ENC, 1024, wsu + U_W8 + W_WA + 1024, 2048, 1024,
                                                     nullptr, nullptr, 0, ws + F_U, 9, Wsv, ws + F_E);
    else
        mfma_gemm<2, 1, 0><<<2048, 256, 0, stream>>>(enc, 1024, wsu + U_W8 + W_WA + 1024, 2048, 1024,
                                                     nullptr, nullptr, 0, ws + F_U, 9, Wsv, ws + F_E);

    k_softmax<<<B, 256, 0, stream>>>(ws + F_E, seqm, ws + F_AT);
    if (full) k_ctx_part<1><<<dim3(B, 4), 256, 0, stream>>>(ws + F_AT, wsu + U_ENC, ws + F_CP);
    else      k_ctx_part<0><<<dim3(B, 4), 256, 0, stream>>>(ws + F_AT, enc, ws + F_CP);
    k_ctx_reduce<<<128, 256, 0, stream>>>(ws + F_CP, wsu + U_NODE, o_ctx, wsu + U_NC);

    // leaf = tanh([node|ctx] @ Wleaf^T + bleaf)
    if (full)
        mfma_gemm<1, 0, 0><<<8, 256, 0, stream>>>(wsu + U_NC, 2048, wsu + U_W8 + W_WLEAF, 2048, 2048,
                                                  bleaf, ws + F_LEAF, 1024, nullptr, 0, nullptr, nullptr);
    else
        mfma_gemm<1, 0, 1><<<8, 256, 0, stream>>>(wsu + U_NC, 2048, Wleaf, 2048, 2048,
                                                  bleaf, ws + F_LEAF, 1024, nullptr, 0, nullptr, nullptr);

    k_build_En<<<2304, 256, 0, stream>>>(ws + F_LEAF, cemb, pades, wsu + uEN, o_cn);
    k_build_Eo<<<384, 256, 0, stream>>>(ws + F_LEAF, oemb, wsu + uEO);
    k_copy_op<<<20, 256, 0, stream>>>(oemb, o_oe);

    // head scores (fused epilogue, atomic)
    mfma_gemm<2, 0, 0><<<144, 256, 0, stream>>>(wsu + uEN, 3072, wsu + U_W8 + W_WNA, 3072, 3072,
                                                nullptr, nullptr, 0, bna, 30, Wns, ws + F_NSC);
    mfma_gemm<2, 0, 0><<<24, 256, 0, stream>>>(wsu + uEO, 3072, wsu + U_W8 + W_WOA, 3072, 3072,
                                               nullptr, nullptr, 0, boa, 30, Wos, ws + F_OSC);

    k_finalize<<<10, 256, 0, stream>>>(ws + F_NSC, ws + F_OSC, masknums, out);
}